// Round 1
// baseline (249.324 us; speedup 1.0000x reference)
//
#include <hip/hip_runtime.h>
#include <math.h>

// Problem constants (fixed by setup_inputs)
#define HD 32
#define BB 256
#define SS 4096
#define CHUNK 512
#define NC (SS / CHUNK)   // 8 chunks per row
#define BLK 256           // threads per block
#define PART_STRIDE 34    // floats per (b,chunk) partial: m, l, ctx[32]

__device__ __forceinline__ float tanh_fast(float x) {
  // tanh(x) = 1 - 2/(exp(2x)+1); exp via hardware exp2, rcp via v_rcp_f32.
  float e = __builtin_amdgcn_exp2f(x * 2.8853900817779268f); // 2*log2(e)
  return 1.0f - 2.0f * __builtin_amdgcn_rcpf(e + 1.0f);
}
__device__ __forceinline__ float exp_fast(float x) {
  return __builtin_amdgcn_exp2f(x * 1.4426950408889634f);    // log2(e)
}

// Phase 1: one block per (row b, chunk of 512 positions).
// Computes keys for its chunk (lstm read exactly once), scores -> d_out scores
// region (raw), block softmax stats + unnormalized context -> partials ws.
__global__ void __launch_bounds__(BLK) bahdanau_p1(
    const float* __restrict__ lstm, const float* __restrict__ fh,
    const float* __restrict__ Wq, const float* __restrict__ bq,
    const float* __restrict__ Wk, const float* __restrict__ bk,
    const float* __restrict__ Wv, const float* __restrict__ bv,
    float* __restrict__ scores_out, float* __restrict__ partials) {
  __shared__ float sWk[HD * HD];   // [j][h], 4 KB, read as broadcast float4
  __shared__ float sQ[HD];         // query row for this b
  __shared__ float sWv[HD];
  __shared__ float sBk[HD];
  __shared__ float sRedM[BLK / 64];
  __shared__ float sRedL[BLK / 64];
  __shared__ float sRedC[BLK / 64][HD];

  const int tid = threadIdx.x;
  const int b = blockIdx.x / NC;
  const int chunk = blockIdx.x % NC;
  const int base = chunk * CHUNK;

  // Stage Wk (1024 floats = 256 float4, one per thread)
  ((float4*)sWk)[tid] = ((const float4*)Wk)[tid];
  if (tid < HD) {
    sWv[tid] = Wv[tid];
    sBk[tid] = bk[tid];
    // query[h] = bq[h] + sum_j fh[b,j] * Wq[j,h]  (tiny, once per block)
    float acc = bq[tid];
    const float* fhb = fh + b * HD;
#pragma unroll
    for (int j = 0; j < HD; j++) acc += fhb[j] * Wq[j * HD + tid];
    sQ[tid] = acc;
  }
  __syncthreads();

  // Each thread owns 2 positions: sA = base+tid, sB = sA+256 (coalesced rows)
  const int sA = base + tid;
  const int sB = sA + BLK;
  const float* rowA = lstm + ((size_t)b * SS + sA) * HD;
  const float* rowB = rowA + (size_t)BLK * HD;

  float4 xA[8], xB[8];
#pragma unroll
  for (int q = 0; q < 8; q++) {
    xA[q] = ((const float4*)rowA)[q];
    xB[q] = ((const float4*)rowB)[q];
  }

  float keyA[HD], keyB[HD];
#pragma unroll
  for (int q = 0; q < 8; q++) {
    float4 b4 = ((const float4*)sBk)[q];
    keyA[4 * q + 0] = b4.x; keyA[4 * q + 1] = b4.y;
    keyA[4 * q + 2] = b4.z; keyA[4 * q + 3] = b4.w;
    keyB[4 * q + 0] = b4.x; keyB[4 * q + 1] = b4.y;
    keyB[4 * q + 2] = b4.z; keyB[4 * q + 3] = b4.w;
  }

  // keys += x @ Wk : 1 broadcast b128 of Wk per 8 FMAs (2 positions share it)
#pragma unroll
  for (int jq = 0; jq < 8; jq++) {
    const float a4[4] = {xA[jq].x, xA[jq].y, xA[jq].z, xA[jq].w};
    const float c4[4] = {xB[jq].x, xB[jq].y, xB[jq].z, xB[jq].w};
#pragma unroll
    for (int jj = 0; jj < 4; jj++) {
      const float aj = a4[jj];
      const float cj = c4[jj];
      const float* wrow = sWk + (jq * 4 + jj) * HD;
#pragma unroll
      for (int hq = 0; hq < 8; hq++) {
        float4 w = ((const float4*)wrow)[hq];
        keyA[4 * hq + 0] += aj * w.x; keyA[4 * hq + 1] += aj * w.y;
        keyA[4 * hq + 2] += aj * w.z; keyA[4 * hq + 3] += aj * w.w;
        keyB[4 * hq + 0] += cj * w.x; keyB[4 * hq + 1] += cj * w.y;
        keyB[4 * hq + 2] += cj * w.z; keyB[4 * hq + 3] += cj * w.w;
      }
    }
  }

  // scores
  const float bv0 = bv[0];
  float scA = bv0, scB = bv0;
#pragma unroll
  for (int h = 0; h < HD; h++) {
    const float q = sQ[h], wv = sWv[h];
    scA += tanh_fast(q + keyA[h]) * wv;
    scB += tanh_fast(q + keyB[h]) * wv;
  }
  scores_out[(size_t)b * SS + sA] = scA;  // raw scores; normalized in phase 2
  scores_out[(size_t)b * SS + sB] = scB;

  // Block-exact softmax stats over the chunk's 512 scores
  const int wid = tid >> 6, lane = tid & 63;
  float m = fmaxf(scA, scB);
#pragma unroll
  for (int off = 32; off >= 1; off >>= 1) m = fmaxf(m, __shfl_xor(m, off, 64));
  if (lane == 0) sRedM[wid] = m;
  __syncthreads();
  m = fmaxf(fmaxf(sRedM[0], sRedM[1]), fmaxf(sRedM[2], sRedM[3]));

  const float eA = exp_fast(scA - m);
  const float eB = exp_fast(scB - m);
  float l = eA + eB;
#pragma unroll
  for (int off = 32; off >= 1; off >>= 1) l += __shfl_xor(l, off, 64);
  if (lane == 0) sRedL[wid] = l;

  // Unnormalized context: ctx[h] = sum_s e_s * key[s,h] (butterfly per h)
#pragma unroll
  for (int h = 0; h < HD; h++) {
    float v = eA * keyA[h] + eB * keyB[h];
#pragma unroll
    for (int off = 32; off >= 1; off >>= 1) v += __shfl_xor(v, off, 64);
    if (lane == 0) sRedC[wid][h] = v;
  }
  __syncthreads();

  if (tid < HD) {
    float c = sRedC[0][tid] + sRedC[1][tid] + sRedC[2][tid] + sRedC[3][tid];
    float* p = partials + (size_t)(b * NC + chunk) * PART_STRIDE;
    p[2 + tid] = c;
    if (tid == 0) {
      p[0] = m;
      p[1] = sRedL[0] + sRedL[1] + sRedL[2] + sRedL[3];
    }
  }
}

// Phase 2: one block per row b. Merge 8 chunk partials -> (m, L, context),
// write context, normalize raw scores -> att_weights in place.
__global__ void __launch_bounds__(BLK) bahdanau_p2(
    const float* __restrict__ partials, float* __restrict__ ctx_out,
    float* __restrict__ scores) {
  const int b = blockIdx.x;
  const int tid = threadIdx.x;
  __shared__ float sM, sInvL;
  __shared__ float sAl[NC];

  if (tid == 0) {
    float m = -1e30f;
    for (int c = 0; c < NC; c++)
      m = fmaxf(m, partials[(size_t)(b * NC + c) * PART_STRIDE]);
    float L = 0.f;
    for (int c = 0; c < NC; c++) {
      const float* p = partials + (size_t)(b * NC + c) * PART_STRIDE;
      float a = exp_fast(p[0] - m);
      sAl[c] = a;
      L += a * p[1];
    }
    sM = m;
    sInvL = __builtin_amdgcn_rcpf(L);
  }
  __syncthreads();
  const float m = sM, invL = sInvL;

  if (tid < HD) {
    float c = 0.f;
#pragma unroll
    for (int cc = 0; cc < NC; cc++)
      c += sAl[cc] * partials[(size_t)(b * NC + cc) * PART_STRIDE + 2 + tid];
    ctx_out[b * HD + tid] = c * invL;
  }

  float* srow = scores + (size_t)b * SS;
  for (int s = tid; s < SS; s += BLK) {
    srow[s] = exp_fast(srow[s] - m) * invL;
  }
}

extern "C" void kernel_launch(void* const* d_in, const int* in_sizes, int n_in,
                              void* d_out, int out_size, void* d_ws,
                              size_t ws_size, hipStream_t stream) {
  const float* lstm = (const float*)d_in[0];
  const float* fh   = (const float*)d_in[1];
  const float* Wq   = (const float*)d_in[2];
  const float* bq   = (const float*)d_in[3];
  const float* Wk   = (const float*)d_in[4];
  const float* bk   = (const float*)d_in[5];
  const float* Wv   = (const float*)d_in[6];
  const float* bv   = (const float*)d_in[7];

  float* out = (float*)d_out;
  float* ctx_out = out;           // context: B*H floats
  float* scores = out + BB * HD;  // att_weights region, used as raw-score scratch
  float* partials = (float*)d_ws; // B*NC*PART_STRIDE floats (~272 KB)

  bahdanau_p1<<<BB * NC, BLK, 0, stream>>>(lstm, fh, Wq, bq, Wk, bk, Wv, bv,
                                           scores, partials);
  bahdanau_p2<<<BB, BLK, 0, stream>>>(partials, ctx_out, scores);
}

// Round 2
// 239.158 us; speedup vs baseline: 1.0425x; 1.0425x over previous
//
#include <hip/hip_runtime.h>
#include <math.h>

// Problem constants (fixed by setup_inputs)
#define HD 32
#define BB 256
#define SS 4096
#define CHUNK 512
#define NC (SS / CHUNK)   // 8 chunks per row
#define BLK 256           // threads per block
#define PART_STRIDE 34    // floats per (b,chunk) partial: m, l, ctx[32]

typedef float vf32 __attribute__((ext_vector_type(32)));

__device__ __forceinline__ float tanh_fast(float x) {
  // tanh(x) = 1 - 2/(exp(2x)+1); exp via hardware exp2, rcp via v_rcp_f32.
  float e = __builtin_amdgcn_exp2f(x * 2.8853900817779268f); // 2*log2(e)
  return 1.0f - 2.0f * __builtin_amdgcn_rcpf(e + 1.0f);
}
__device__ __forceinline__ float exp_fast(float x) {
  return __builtin_amdgcn_exp2f(x * 1.4426950408889634f);    // log2(e)
}

// Phase 1: one block per (row b, chunk of 512 positions), 2 positions/thread.
// Keys in registers (ext_vector), Wk/bk/Wv/bv via wave-uniform scalar loads.
__global__ void __launch_bounds__(BLK, 3) bahdanau_p1(
    const float* __restrict__ lstm, const float* __restrict__ fh,
    const float* __restrict__ Wq, const float* __restrict__ bq,
    const float* __restrict__ Wk, const float* __restrict__ bk,
    const float* __restrict__ Wv, const float* __restrict__ bv,
    float* __restrict__ scores_out, float* __restrict__ partials) {
  __shared__ float sQ[HD];         // query row for this b
  __shared__ float sRedM[BLK / 64];
  __shared__ float sRedL[BLK / 64];
  __shared__ float sRedC[BLK / 64][HD];

  const int tid = threadIdx.x;
  const int b = blockIdx.x / NC;
  const int chunk = blockIdx.x % NC;
  const int base = chunk * CHUNK;

  // Each thread owns 2 positions: sA = base+tid, sB = sA+256
  const int sA = base + tid;
  const int sB = sA + BLK;
  const float* rowA = lstm + ((size_t)b * SS + sA) * HD;
  const float* rowB = rowA + (size_t)BLK * HD;

  // Issue the 16 x-loads first (independent of LDS / scalar work)
  vf32 xA, xB;
#pragma unroll
  for (int q = 0; q < 8; q++) {
    float4 t = ((const float4*)rowA)[q];
    xA[4 * q + 0] = t.x; xA[4 * q + 1] = t.y;
    xA[4 * q + 2] = t.z; xA[4 * q + 3] = t.w;
  }
#pragma unroll
  for (int q = 0; q < 8; q++) {
    float4 t = ((const float4*)rowB)[q];
    xB[4 * q + 0] = t.x; xB[4 * q + 1] = t.y;
    xB[4 * q + 2] = t.z; xB[4 * q + 3] = t.w;
  }

  // query[h] = bq[h] + sum_j fh[b,j] * Wq[j,h]  (tiny, once per block)
  if (tid < HD) {
    float acc = bq[tid];
    const float* fhb = fh + b * HD;
#pragma unroll
    for (int j = 0; j < HD; j++) acc += fhb[j] * Wq[j * HD + tid];
    sQ[tid] = acc;
  }
  __syncthreads();

  // keys = bk + x @ Wk ; Wk[j*32+h] is wave-uniform -> s_load, FMA reads SGPR
  vf32 kA, kB;
#pragma unroll
  for (int h = 0; h < HD; h++) {
    float bkh = bk[h];
    kA[h] = bkh; kB[h] = bkh;
  }
#pragma unroll
  for (int j = 0; j < HD; j++) {
    const float xa = xA[j];
    const float xb = xB[j];
#pragma unroll
    for (int h = 0; h < HD; h++) {
      const float w = Wk[j * HD + h];
      kA[h] = fmaf(xa, w, kA[h]);
      kB[h] = fmaf(xb, w, kB[h]);
    }
  }

  // scores
  const float bv0 = bv[0];
  float scA = bv0, scB = bv0;
#pragma unroll
  for (int h = 0; h < HD; h++) {
    const float qh = sQ[h];      // LDS broadcast
    const float wv = Wv[h];      // scalar
    scA = fmaf(tanh_fast(qh + kA[h]), wv, scA);
    scB = fmaf(tanh_fast(qh + kB[h]), wv, scB);
  }
  scores_out[(size_t)b * SS + sA] = scA;  // raw; normalized in phase 2
  scores_out[(size_t)b * SS + sB] = scB;

  // Block-exact softmax stats over the chunk's 512 scores
  const int wid = tid >> 6, lane = tid & 63;
  float m = fmaxf(scA, scB);
#pragma unroll
  for (int off = 32; off >= 1; off >>= 1) m = fmaxf(m, __shfl_xor(m, off, 64));
  if (lane == 0) sRedM[wid] = m;
  __syncthreads();
  m = fmaxf(fmaxf(sRedM[0], sRedM[1]), fmaxf(sRedM[2], sRedM[3]));

  const float eA = exp_fast(scA - m);
  const float eB = exp_fast(scB - m);
  float l = eA + eB;
#pragma unroll
  for (int off = 32; off >= 1; off >>= 1) l += __shfl_xor(l, off, 64);
  if (lane == 0) sRedL[wid] = l;

  // Unnormalized context: ctx[h] = sum_s e_s * key[s,h] (butterfly per h)
#pragma unroll
  for (int h = 0; h < HD; h++) {
    float v = fmaf(eA, kA[h], eB * kB[h]);
#pragma unroll
    for (int off = 32; off >= 1; off >>= 1) v += __shfl_xor(v, off, 64);
    if (lane == 0) sRedC[wid][h] = v;
  }
  __syncthreads();

  if (tid < HD) {
    float c = sRedC[0][tid] + sRedC[1][tid] + sRedC[2][tid] + sRedC[3][tid];
    float* p = partials + (size_t)(b * NC + chunk) * PART_STRIDE;
    p[2 + tid] = c;
    if (tid == 0) {
      p[0] = m;
      p[1] = sRedL[0] + sRedL[1] + sRedL[2] + sRedL[3];
    }
  }
}

// Phase 2: one block per (row, chunk). All blocks redundantly merge the 8
// chunk partials (scalar loads) -> (m, L); chunk-0 block writes context;
// every block normalizes its 512 raw scores in place.
__global__ void __launch_bounds__(BLK) bahdanau_p2(
    const float* __restrict__ partials, float* __restrict__ ctx_out,
    float* __restrict__ scores) {
  const int b = blockIdx.x / NC;
  const int chunk = blockIdx.x % NC;
  const int tid = threadIdx.x;

  // Merge stats (wave-uniform scalar loads; 8 m's + 8 l's)
  float m = -1e30f;
#pragma unroll
  for (int c = 0; c < NC; c++)
    m = fmaxf(m, partials[(size_t)(b * NC + c) * PART_STRIDE]);
  float L = 0.f;
  float al[NC];
#pragma unroll
  for (int c = 0; c < NC; c++) {
    const float* p = partials + (size_t)(b * NC + c) * PART_STRIDE;
    float a = exp_fast(p[0] - m);
    al[c] = a;
    L = fmaf(a, p[1], L);
  }
  const float invL = __builtin_amdgcn_rcpf(L);

  // Context (only chunk-0 block)
  if (chunk == 0 && tid < HD) {
    float c = 0.f;
#pragma unroll
    for (int cc = 0; cc < NC; cc++)
      c += al[cc] * partials[(size_t)(b * NC + cc) * PART_STRIDE + 2 + tid];
    ctx_out[b * HD + tid] = c * invL;
  }

  // Normalize this chunk's 512 scores (2 per thread, float2)
  float2* srow = (float2*)(scores + (size_t)b * SS + chunk * CHUNK);
  float2 s = srow[tid];
  s.x = exp_fast(s.x - m) * invL;
  s.y = exp_fast(s.y - m) * invL;
  srow[tid] = s;
}

extern "C" void kernel_launch(void* const* d_in, const int* in_sizes, int n_in,
                              void* d_out, int out_size, void* d_ws,
                              size_t ws_size, hipStream_t stream) {
  const float* lstm = (const float*)d_in[0];
  const float* fh   = (const float*)d_in[1];
  const float* Wq   = (const float*)d_in[2];
  const float* bq   = (const float*)d_in[3];
  const float* Wk   = (const float*)d_in[4];
  const float* bk   = (const float*)d_in[5];
  const float* Wv   = (const float*)d_in[6];
  const float* bv   = (const float*)d_in[7];

  float* out = (float*)d_out;
  float* ctx_out = out;           // context: B*H floats
  float* scores = out + BB * HD;  // att_weights region, used as raw-score scratch
  float* partials = (float*)d_ws; // B*NC*PART_STRIDE floats (~272 KB)

  bahdanau_p1<<<BB * NC, BLK, 0, stream>>>(lstm, fh, Wq, bq, Wk, bk, Wv, bv,
                                           scores, partials);
  bahdanau_p2<<<BB * NC, BLK, 0, stream>>>(partials, ctx_out, scores);
}